// Round 13
// baseline (313.087 us; speedup 1.0000x reference)
//
#include <hip/hip_runtime.h>
#include <hip/hip_fp16.h>
#include <cstdint>

#define NCH 128   // IN_CH == OUT_CH == 128
#define NSLICE 8  // 8 col-slices of 16 ch: 100000*16*2B = 3.2 MB/slice < 4 MB L2/XCD

typedef short short8v __attribute__((ext_vector_type(8)));
typedef unsigned short ushort4v __attribute__((ext_vector_type(4)));
typedef float f32x4  __attribute__((ext_vector_type(4)));

// f32 -> bf16 bits, round-to-nearest-even
static __device__ __forceinline__ short f2bf(float f) {
    unsigned u = __float_as_uint(f);
    u += 0x7FFFu + ((u >> 16) & 1u);
    return (short)(u >> 16);
}
static __device__ __forceinline__ unsigned short f2h(float f) {
    return __half_as_ushort(__float2half(f));
}
static __device__ __forceinline__ float h2f(unsigned short u) {
    return __half2float(__ushort_as_half(u));
}

// L2-direct gather (r12; neutral vs plain load, kept so r12's timing equation
// p+g+e=126 holds exactly for this round's subtraction)
static __device__ __forceinline__ ushort4v gather8_l2(const unsigned short* p) {
    unsigned long long v = __hip_atomic_load(
        reinterpret_cast<const unsigned long long*>(p),
        __ATOMIC_RELAXED, __HIP_MEMORY_SCOPE_AGENT);
    return __builtin_bit_cast(ushort4v, v);
}

// ---------------------------------------------------------------------------
// prep: a = softmax(attn_weights); Wpb[o][d] = bf16(W[o][d] * a[d])
// ---------------------------------------------------------------------------
__global__ __launch_bounds__(128)
void prep_kernel(const float* __restrict__ aw,
                 const float* __restrict__ W,
                 short* __restrict__ Wpb) {
    __shared__ float sa[NCH];
    const int t = threadIdx.x;
    const int o = blockIdx.x;
    sa[t] = aw[t];
    __syncthreads();
    float m = -1e30f;
#pragma unroll
    for (int d = 0; d < NCH; ++d) m = fmaxf(m, sa[d]);
    float s = 0.f;
#pragma unroll
    for (int d = 0; d < NCH; ++d) s += expf(sa[d] - m);
    const float av = expf(sa[t] - m) / s;
    Wpb[o * NCH + t] = f2bf(W[o * NCH + t] * av);
}

// ---------------------------------------------------------------------------
// node GEMM via MFMA 16x16x32 bf16, no LDS (round-6 winner) + BIAS/2 FOLD
// (byte-identical to round 12)
// ---------------------------------------------------------------------------
__global__ __launch_bounds__(256)
void node_gemm_mfma(const float* __restrict__ X,
                    const short* __restrict__ Wpb,
                    const float* __restrict__ bias,
                    unsigned short* __restrict__ Ys, int M) {
    const int t    = threadIdx.x;
    const int wave = t >> 6;
    const int lane = t & 63;
    const int r    = lane & 15;
    const int kb   = lane >> 4;

    const int node  = blockIdx.x * 64 + wave * 16 + r;
    const int nodec = node < M ? node : M - 1;       // clamp; stores guarded
    const float* xr = X + (size_t)nodec * NCH;

    short8v b[4];
#pragma unroll
    for (int ks = 0; ks < 4; ++ks) {
        const float4 f0 = *reinterpret_cast<const float4*>(xr + ks * 32 + kb * 8);
        const float4 f1 = *reinterpret_cast<const float4*>(xr + ks * 32 + kb * 8 + 4);
        short8v v;
        v[0] = f2bf(f0.x); v[1] = f2bf(f0.y); v[2] = f2bf(f0.z); v[3] = f2bf(f0.w);
        v[4] = f2bf(f1.x); v[5] = f2bf(f1.y); v[6] = f2bf(f1.z); v[7] = f2bf(f1.w);
        b[ks] = v;
    }

#pragma unroll
    for (int tile = 0; tile < 8; ++tile) {
        f32x4 acc = {0.f, 0.f, 0.f, 0.f};
        const short* wr = Wpb + (size_t)(tile * 16 + r) * NCH;
#pragma unroll
        for (int ks = 0; ks < 4; ++ks) {
            const short8v a = *reinterpret_cast<const short8v*>(wr + ks * 32 + kb * 8);
            acc = __builtin_amdgcn_mfma_f32_16x16x32_bf16(a, b[ks], acc, 0, 0, 0);
        }
        if (node < M) {
            const float4 vb = *reinterpret_cast<const float4*>(bias + tile * 16 + kb * 4);
            ushort4v h;
            h[0] = f2h(acc[0] + 0.5f * vb.x);
            h[1] = f2h(acc[1] + 0.5f * vb.y);
            h[2] = f2h(acc[2] + 0.5f * vb.z);
            h[3] = f2h(acc[3] + 0.5f * vb.w);
            *reinterpret_cast<ushort4v*>(
                Ys + (size_t)tile * M * 16 + (size_t)node * 16 + kb * 4) = h;
        }
    }
}

// ---------------------------------------------------------------------------
// sliced edge kernel (byte-identical to round 12)
// ---------------------------------------------------------------------------
__global__ __launch_bounds__(256)
void edge_out_sliced(const unsigned short* __restrict__ Ys,
                     const int* __restrict__ ei,
                     float* __restrict__ out, int E, int M) {
    const unsigned bid = blockIdx.x;
    const int slice = bid & (NSLICE - 1);
    const int eblk  = bid >> 3;
    const int t  = threadIdx.x;
    const int cl = t & 3;
    const int e0 = eblk * 256 + (t >> 2);      // edges e0 + k*64, k=0..3

    const unsigned short* base = Ys + (size_t)slice * M * 16 + cl * 4;

    int s[4], g[4];
#pragma unroll
    for (int k = 0; k < 4; ++k) {
        const int e = e0 + k * 64;
        const int ec = e < E ? e : 0;
        s[k] = ei[ec];
        g[k] = ei[E + ec];
    }
    ushort4v hs[4], ht[4];
#pragma unroll
    for (int k = 0; k < 4; ++k) {
        hs[k] = gather8_l2(base + (size_t)s[k] * 16);
        ht[k] = gather8_l2(base + (size_t)g[k] * 16);
    }
#pragma unroll
    for (int k = 0; k < 4; ++k) {
        const int e = e0 + k * 64;
        if (e < E) {
            f32x4 r;
            r[0] = fmaxf(h2f(hs[k][0]) + h2f(ht[k][0]), 0.f);
            r[1] = fmaxf(h2f(hs[k][1]) + h2f(ht[k][1]), 0.f);
            r[2] = fmaxf(h2f(hs[k][2]) + h2f(ht[k][2]), 0.f);
            r[3] = fmaxf(h2f(hs[k][3]) + h2f(ht[k][3]), 0.f);
            f32x4* dst = reinterpret_cast<f32x4*>(
                out + (size_t)e * NCH + slice * 16 + cl * 4);
            __builtin_nontemporal_store(r, dst);
        }
    }
}

// ---------------------------------------------------------------------------
// fallback (only if ws too small): fully self-contained direct fp32 edge GEMM
// ---------------------------------------------------------------------------
__global__ __launch_bounds__(256)
void direct_edge_kernel(const float* __restrict__ X,
                        const int* __restrict__ ei,
                        const float* __restrict__ aw,
                        const float* __restrict__ W,
                        const float* __restrict__ bias,
                        float* __restrict__ out, int E) {
    __shared__ float sW[NCH][NCH + 1];
    __shared__ float sa[NCH];
    __shared__ float sE[8][NCH + 4];
    const int t = threadIdx.x;
    if (t < NCH) sa[t] = aw[t];
    __syncthreads();
    float m = -1e30f;
#pragma unroll
    for (int d = 0; d < NCH; ++d) m = fmaxf(m, sa[d]);
    float ssum = 0.f;
#pragma unroll
    for (int d = 0; d < NCH; ++d) ssum += expf(sa[d] - m);
    const float av = (t < NCH) ? expf(sa[t] - m) / ssum : 0.f;
    __syncthreads();
    if (t < NCH) sa[t] = av;
    __syncthreads();
    for (int i = t; i < NCH * 32; i += 256) {
        const int o = i >> 5, q = i & 31;
        float4 v = reinterpret_cast<const float4*>(W)[o * 32 + q];
        sW[o][q * 4 + 0] = v.x * sa[q * 4 + 0];
        sW[o][q * 4 + 1] = v.y * sa[q * 4 + 1];
        sW[o][q * 4 + 2] = v.z * sa[q * 4 + 2];
        sW[o][q * 4 + 3] = v.w * sa[q * 4 + 3];
    }
    __syncthreads();
    const int le = t >> 5, q = t & 31;
    for (int e0 = blockIdx.x * 8; e0 < E; e0 += gridDim.x * 8) {
        const int e = e0 + le;
        if (e < E) {
            const int s = ei[e];
            const int g = ei[E + e];
            const float4 vs = reinterpret_cast<const float4*>(X)[(size_t)s * 32 + q];
            const float4 vt = reinterpret_cast<const float4*>(X)[(size_t)g * 32 + q];
            sE[le][q * 4 + 0] = vs.x + vt.x;
            sE[le][q * 4 + 1] = vs.y + vt.y;
            sE[le][q * 4 + 2] = vs.z + vt.z;
            sE[le][q * 4 + 3] = vs.w + vt.w;
        }
        __syncthreads();
        if (e < E) {
            float a0 = 0.f, a1 = 0.f, a2 = 0.f, a3 = 0.f;
            const int o = q * 4;
#pragma unroll 4
            for (int d = 0; d < NCH; ++d) {
                const float x = sE[le][d];
                a0 += x * sW[o + 0][d];
                a1 += x * sW[o + 1][d];
                a2 += x * sW[o + 2][d];
                a3 += x * sW[o + 3][d];
            }
            float4 r;
            r.x = fmaxf(a0 + bias[o + 0], 0.f);
            r.y = fmaxf(a1 + bias[o + 1], 0.f);
            r.z = fmaxf(a2 + bias[o + 2], 0.f);
            r.w = fmaxf(a3 + bias[o + 3], 0.f);
            reinterpret_cast<float4*>(out)[(size_t)e * 32 + q] = r;
        }
        __syncthreads();
    }
}

// ---------------------------------------------------------------------------
// MEASUREMENT ROUND: launches = prep, gemm, gemm, edge, edge, edge.
// All duplicates are idempotent (same inputs -> same writes), so output and
// determinism are unchanged. With r12's p+g+e=126 and p~2:
//   edge = dur - 250,  gemm = 124 - edge.
// ---------------------------------------------------------------------------
extern "C" void kernel_launch(void* const* d_in, const int* in_sizes, int n_in,
                              void* d_out, int out_size, void* d_ws, size_t ws_size,
                              hipStream_t stream) {
    const float* X    = (const float*)d_in[0];   // [100000,128] f32
    const int*   ei   = (const int*)d_in[1];     // [2,625000] int32
    const float* aw   = (const float*)d_in[2];   // [128] f32
    const float* W    = (const float*)d_in[3];   // [128,128] f32
    const float* bias = (const float*)d_in[4];   // [128] f32
    float* out = (float*)d_out;

    const int M = in_sizes[0] / NCH;             // 100000 nodes
    const int E = in_sizes[1] / 2;               // 625000 edges

    const size_t y_off   = 65536;                                    // Wpb (32KB) + pad
    const size_t y_bytes = (size_t)M * NCH * sizeof(unsigned short); // 25.6 MB sliced

    if (ws_size >= y_off + y_bytes) {
        short* Wpb = (short*)d_ws;
        unsigned short* Ys = (unsigned short*)((char*)d_ws + y_off);
        prep_kernel<<<NCH, 128, 0, stream>>>(aw, W, Wpb);
        node_gemm_mfma<<<(M + 63) / 64, 256, 0, stream>>>(X, Wpb, bias, Ys, M);
        node_gemm_mfma<<<(M + 63) / 64, 256, 0, stream>>>(X, Wpb, bias, Ys, M);
        const int eblks = (E + 255) / 256;
        edge_out_sliced<<<eblks * NSLICE, 256, 0, stream>>>(Ys, ei, out, E, M);
        edge_out_sliced<<<eblks * NSLICE, 256, 0, stream>>>(Ys, ei, out, E, M);
        edge_out_sliced<<<eblks * NSLICE, 256, 0, stream>>>(Ys, ei, out, E, M);
    } else {
        int grid = (E + 7) / 8;
        if (grid > 32768) grid = 32768;
        direct_edge_kernel<<<grid, 256, 0, stream>>>(X, ei, aw, W, bias, out, E);
    }
}

// Round 14
// 106.759 us; speedup vs baseline: 2.9327x; 2.9327x over previous
//
#include <hip/hip_runtime.h>
#include <hip/hip_fp16.h>
#include <cstdint>

#define NCH 128   // IN_CH == OUT_CH == 128
#define NSLICE 8  // 8 col-slices of 16 ch: 100000*16*2B = 3.2 MB/slice < 4 MB L2/XCD

typedef short short8v __attribute__((ext_vector_type(8)));
typedef unsigned short ushort4v __attribute__((ext_vector_type(4)));
typedef float f32x4  __attribute__((ext_vector_type(4)));

// f32 -> bf16 bits, round-to-nearest-even
static __device__ __forceinline__ short f2bf(float f) {
    unsigned u = __float_as_uint(f);
    u += 0x7FFFu + ((u >> 16) & 1u);
    return (short)(u >> 16);
}
static __device__ __forceinline__ unsigned short f2h(float f) {
    return __half_as_ushort(__float2half(f));
}
static __device__ __forceinline__ float h2f(unsigned short u) {
    return __half2float(__ushort_as_half(u));
}

// L2-direct gather (r12: neutral vs plain load; kept — part of champion config)
static __device__ __forceinline__ ushort4v gather8_l2(const unsigned short* p) {
    unsigned long long v = __hip_atomic_load(
        reinterpret_cast<const unsigned long long*>(p),
        __ATOMIC_RELAXED, __HIP_MEMORY_SCOPE_AGENT);
    return __builtin_bit_cast(ushort4v, v);
}

// ---------------------------------------------------------------------------
// prep: a = softmax(attn_weights); Wpb[o][d] = bf16(W[o][d] * a[d])
// ---------------------------------------------------------------------------
__global__ __launch_bounds__(128)
void prep_kernel(const float* __restrict__ aw,
                 const float* __restrict__ W,
                 short* __restrict__ Wpb) {
    __shared__ float sa[NCH];
    const int t = threadIdx.x;
    const int o = blockIdx.x;
    sa[t] = aw[t];
    __syncthreads();
    float m = -1e30f;
#pragma unroll
    for (int d = 0; d < NCH; ++d) m = fmaxf(m, sa[d]);
    float s = 0.f;
#pragma unroll
    for (int d = 0; d < NCH; ++d) s += expf(sa[d] - m);
    const float av = expf(sa[t] - m) / s;
    Wpb[o * NCH + t] = f2bf(W[o * NCH + t] * av);
}

// ---------------------------------------------------------------------------
// node GEMM, RESTRUCTURED (r13 measurement: gemm was ~50-60us, 4-5x its
// traffic floor; cause hypothesis = per-MFMA W-loads falling to L2 because
// X streaming thrashes L1).
//  - Wpb staged in LDS once per block (32KB), XOR-swizzled: chunk col (16B
//    units) ^= (row&7) so the 16-lane 256B-strided ds_read_b128 is 2-way
//    (free, m136) instead of 16-way conflicted.
//  - 2 node-groups per wave: each a-frag ds_read feeds 2 MFMAs.
//  - block = 256 thr (4 waves) x 32 nodes/wave = 128 nodes; grid = 782.
// Output layout, bias/2 fold, packed 8B stores: identical to r12 (bit-same).
// ---------------------------------------------------------------------------
__global__ __launch_bounds__(256)
void node_gemm_mfma(const float* __restrict__ X,
                    const short* __restrict__ Wpb,
                    const float* __restrict__ bias,
                    unsigned short* __restrict__ Ys, int M) {
    __shared__ short sW[NCH * NCH];          // 32 KB, swizzled 16B chunks
    const int t = threadIdx.x;

    // stage Wpb -> LDS: 2048 chunks of 16B; global read coalesced,
    // LDS chunk col swizzled: scc = cc ^ (row&7)
    for (int it = 0; it < 8; ++it) {
        const int j   = it * 256 + t;        // chunk index
        const int row = j >> 4;
        const int cc  = j & 15;
        const int scc = cc ^ (row & 7);
        *reinterpret_cast<short8v*>(&sW[row * NCH + scc * 8]) =
            *reinterpret_cast<const short8v*>(Wpb + (size_t)j * 8);
    }
    __syncthreads();

    const int wave = t >> 6;
    const int lane = t & 63;
    const int r    = lane & 15;
    const int kb   = lane >> 4;

    const int nbase = blockIdx.x * 128 + wave * 32;

    // B-fragments (X rows) for 2 node groups
    short8v b[2][4];
    int node[2];
#pragma unroll
    for (int ng = 0; ng < 2; ++ng) {
        node[ng] = nbase + ng * 16 + r;
        const int nodec = node[ng] < M ? node[ng] : M - 1;   // stores guarded
        const float* xr = X + (size_t)nodec * NCH;
#pragma unroll
        for (int ks = 0; ks < 4; ++ks) {
            const float4 f0 = *reinterpret_cast<const float4*>(xr + ks * 32 + kb * 8);
            const float4 f1 = *reinterpret_cast<const float4*>(xr + ks * 32 + kb * 8 + 4);
            short8v v;
            v[0] = f2bf(f0.x); v[1] = f2bf(f0.y); v[2] = f2bf(f0.z); v[3] = f2bf(f0.w);
            v[4] = f2bf(f1.x); v[5] = f2bf(f1.y); v[6] = f2bf(f1.z); v[7] = f2bf(f1.w);
            b[ng][ks] = v;
        }
    }

#pragma unroll
    for (int tile = 0; tile < 8; ++tile) {
        f32x4 acc0 = {0.f, 0.f, 0.f, 0.f};
        f32x4 acc1 = {0.f, 0.f, 0.f, 0.f};
        const int row = tile * 16 + r;
#pragma unroll
        for (int ks = 0; ks < 4; ++ks) {
            const int cc = ks * 4 + kb;                       // unswizzled chunk col
            const short8v a = *reinterpret_cast<const short8v*>(
                &sW[row * NCH + (cc ^ (row & 7)) * 8]);
            acc0 = __builtin_amdgcn_mfma_f32_16x16x32_bf16(a, b[0][ks], acc0, 0, 0, 0);
            acc1 = __builtin_amdgcn_mfma_f32_16x16x32_bf16(a, b[1][ks], acc1, 0, 0, 0);
        }
        const float4 vb = *reinterpret_cast<const float4*>(bias + tile * 16 + kb * 4);
        if (node[0] < M) {
            ushort4v h;
            h[0] = f2h(acc0[0] + 0.5f * vb.x);
            h[1] = f2h(acc0[1] + 0.5f * vb.y);
            h[2] = f2h(acc0[2] + 0.5f * vb.z);
            h[3] = f2h(acc0[3] + 0.5f * vb.w);
            *reinterpret_cast<ushort4v*>(
                Ys + (size_t)tile * M * 16 + (size_t)node[0] * 16 + kb * 4) = h;
        }
        if (node[1] < M) {
            ushort4v h;
            h[0] = f2h(acc1[0] + 0.5f * vb.x);
            h[1] = f2h(acc1[1] + 0.5f * vb.y);
            h[2] = f2h(acc1[2] + 0.5f * vb.z);
            h[3] = f2h(acc1[3] + 0.5f * vb.w);
            *reinterpret_cast<ushort4v*>(
                Ys + (size_t)tile * M * 16 + (size_t)node[1] * 16 + kb * 4) = h;
        }
    }
}

// ---------------------------------------------------------------------------
// sliced edge kernel (byte-identical to r12 champion; r13 showed it is within
// ~10% of its write+gather floor — do not touch)
// ---------------------------------------------------------------------------
__global__ __launch_bounds__(256)
void edge_out_sliced(const unsigned short* __restrict__ Ys,
                     const int* __restrict__ ei,
                     float* __restrict__ out, int E, int M) {
    const unsigned bid = blockIdx.x;
    const int slice = bid & (NSLICE - 1);
    const int eblk  = bid >> 3;
    const int t  = threadIdx.x;
    const int cl = t & 3;
    const int e0 = eblk * 256 + (t >> 2);      // edges e0 + k*64, k=0..3

    const unsigned short* base = Ys + (size_t)slice * M * 16 + cl * 4;

    int s[4], g[4];
#pragma unroll
    for (int k = 0; k < 4; ++k) {
        const int e = e0 + k * 64;
        const int ec = e < E ? e : 0;
        s[k] = ei[ec];
        g[k] = ei[E + ec];
    }
    ushort4v hs[4], ht[4];
#pragma unroll
    for (int k = 0; k < 4; ++k) {
        hs[k] = gather8_l2(base + (size_t)s[k] * 16);
        ht[k] = gather8_l2(base + (size_t)g[k] * 16);
    }
#pragma unroll
    for (int k = 0; k < 4; ++k) {
        const int e = e0 + k * 64;
        if (e < E) {
            f32x4 r;
            r[0] = fmaxf(h2f(hs[k][0]) + h2f(ht[k][0]), 0.f);
            r[1] = fmaxf(h2f(hs[k][1]) + h2f(ht[k][1]), 0.f);
            r[2] = fmaxf(h2f(hs[k][2]) + h2f(ht[k][2]), 0.f);
            r[3] = fmaxf(h2f(hs[k][3]) + h2f(ht[k][3]), 0.f);
            f32x4* dst = reinterpret_cast<f32x4*>(
                out + (size_t)e * NCH + slice * 16 + cl * 4);
            __builtin_nontemporal_store(r, dst);
        }
    }
}

// ---------------------------------------------------------------------------
// fallback (only if ws too small): fully self-contained direct fp32 edge GEMM
// ---------------------------------------------------------------------------
__global__ __launch_bounds__(256)
void direct_edge_kernel(const float* __restrict__ X,
                        const int* __restrict__ ei,
                        const float* __restrict__ aw,
                        const float* __restrict__ W,
                        const float* __restrict__ bias,
                        float* __restrict__ out, int E) {
    __shared__ float sW[NCH][NCH + 1];
    __shared__ float sa[NCH];
    __shared__ float sE[8][NCH + 4];
    const int t = threadIdx.x;
    if (t < NCH) sa[t] = aw[t];
    __syncthreads();
    float m = -1e30f;
#pragma unroll
    for (int d = 0; d < NCH; ++d) m = fmaxf(m, sa[d]);
    float ssum = 0.f;
#pragma unroll
    for (int d = 0; d < NCH; ++d) ssum += expf(sa[d] - m);
    const float av = (t < NCH) ? expf(sa[t] - m) / ssum : 0.f;
    __syncthreads();
    if (t < NCH) sa[t] = av;
    __syncthreads();
    for (int i = t; i < NCH * 32; i += 256) {
        const int o = i >> 5, q = i & 31;
        float4 v = reinterpret_cast<const float4*>(W)[o * 32 + q];
        sW[o][q * 4 + 0] = v.x * sa[q * 4 + 0];
        sW[o][q * 4 + 1] = v.y * sa[q * 4 + 1];
        sW[o][q * 4 + 2] = v.z * sa[q * 4 + 2];
        sW[o][q * 4 + 3] = v.w * sa[q * 4 + 3];
    }
    __syncthreads();
    const int le = t >> 5, q = t & 31;
    for (int e0 = blockIdx.x * 8; e0 < E; e0 += gridDim.x * 8) {
        const int e = e0 + le;
        if (e < E) {
            const int s = ei[e];
            const int g = ei[E + e];
            const float4 vs = reinterpret_cast<const float4*>(X)[(size_t)s * 32 + q];
            const float4 vt = reinterpret_cast<const float4*>(X)[(size_t)g * 32 + q];
            sE[le][q * 4 + 0] = vs.x + vt.x;
            sE[le][q * 4 + 1] = vs.y + vt.y;
            sE[le][q * 4 + 2] = vs.z + vt.z;
            sE[le][q * 4 + 3] = vs.w + vt.w;
        }
        __syncthreads();
        if (e < E) {
            float a0 = 0.f, a1 = 0.f, a2 = 0.f, a3 = 0.f;
            const int o = q * 4;
#pragma unroll 4
            for (int d = 0; d < NCH; ++d) {
                const float x = sE[le][d];
                a0 += x * sW[o + 0][d];
                a1 += x * sW[o + 1][d];
                a2 += x * sW[o + 2][d];
                a3 += x * sW[o + 3][d];
            }
            float4 r;
            r.x = fmaxf(a0 + bias[o + 0], 0.f);
            r.y = fmaxf(a1 + bias[o + 1], 0.f);
            r.z = fmaxf(a2 + bias[o + 2], 0.f);
            r.w = fmaxf(a3 + bias[o + 3], 0.f);
            reinterpret_cast<float4*>(out)[(size_t)e * 32 + q] = r;
        }
        __syncthreads();
    }
}

// ---------------------------------------------------------------------------
extern "C" void kernel_launch(void* const* d_in, const int* in_sizes, int n_in,
                              void* d_out, int out_size, void* d_ws, size_t ws_size,
                              hipStream_t stream) {
    const float* X    = (const float*)d_in[0];   // [100000,128] f32
    const int*   ei   = (const int*)d_in[1];     // [2,625000] int32
    const float* aw   = (const float*)d_in[2];   // [128] f32
    const float* W    = (const float*)d_in[3];   // [128,128] f32
    const float* bias = (const float*)d_in[4];   // [128] f32
    float* out = (float*)d_out;

    const int M = in_sizes[0] / NCH;             // 100000 nodes
    const int E = in_sizes[1] / 2;               // 625000 edges

    const size_t y_off   = 65536;                                    // Wpb (32KB) + pad
    const size_t y_bytes = (size_t)M * NCH * sizeof(unsigned short); // 25.6 MB sliced

    if (ws_size >= y_off + y_bytes) {
        short* Wpb = (short*)d_ws;
        unsigned short* Ys = (unsigned short*)((char*)d_ws + y_off);
        prep_kernel<<<NCH, 128, 0, stream>>>(aw, W, Wpb);
        node_gemm_mfma<<<(M + 127) / 128, 256, 0, stream>>>(X, Wpb, bias, Ys, M);
        const int eblks = (E + 255) / 256;
        edge_out_sliced<<<eblks * NSLICE, 256, 0, stream>>>(Ys, ei, out, E, M);
    } else {
        int grid = (E + 7) / 8;
        if (grid > 32768) grid = 32768;
        direct_edge_kernel<<<grid, 256, 0, stream>>>(X, ei, aw, W, bias, out, E);
    }
}

// Round 15
// 106.148 us; speedup vs baseline: 2.9495x; 1.0058x over previous
//
#include <hip/hip_runtime.h>
#include <hip/hip_fp16.h>
#include <cstdint>

#define NCH 128   // IN_CH == OUT_CH == 128
#define NSLICE 8  // 8 col-slices of 16 ch: 100000*16*2B = 3.2 MB/slice < 4 MB L2/XCD

typedef short short8v __attribute__((ext_vector_type(8)));
typedef unsigned short ushort4v __attribute__((ext_vector_type(4)));
typedef float f32x4  __attribute__((ext_vector_type(4)));

// f32 -> bf16 bits, round-to-nearest-even
static __device__ __forceinline__ short f2bf(float f) {
    unsigned u = __float_as_uint(f);
    u += 0x7FFFu + ((u >> 16) & 1u);
    return (short)(u >> 16);
}
static __device__ __forceinline__ unsigned short f2h(float f) {
    return __half_as_ushort(__float2half(f));
}
static __device__ __forceinline__ float h2f(unsigned short u) {
    return __half2float(__ushort_as_half(u));
}

// L2-direct gather (r12: neutral vs plain load; part of champion config)
static __device__ __forceinline__ ushort4v gather8_l2(const unsigned short* p) {
    unsigned long long v = __hip_atomic_load(
        reinterpret_cast<const unsigned long long*>(p),
        __ATOMIC_RELAXED, __HIP_MEMORY_SCOPE_AGENT);
    return __builtin_bit_cast(ushort4v, v);
}

// ---------------------------------------------------------------------------
// prep: a = softmax(attn_weights); Wpb[o][d] = bf16(W[o][d] * a[d])
// ---------------------------------------------------------------------------
__global__ __launch_bounds__(128)
void prep_kernel(const float* __restrict__ aw,
                 const float* __restrict__ W,
                 short* __restrict__ Wpb) {
    __shared__ float sa[NCH];
    const int t = threadIdx.x;
    const int o = blockIdx.x;
    sa[t] = aw[t];
    __syncthreads();
    float m = -1e30f;
#pragma unroll
    for (int d = 0; d < NCH; ++d) m = fmaxf(m, sa[d]);
    float s = 0.f;
#pragma unroll
    for (int d = 0; d < NCH; ++d) s += expf(sa[d] - m);
    const float av = expf(sa[t] - m) / s;
    Wpb[o * NCH + t] = f2bf(W[o * NCH + t] * av);
}

// ---------------------------------------------------------------------------
// node GEMM v3: LDS-staged swizzled W (r14 winner) + 4 NODE-GROUPS per wave.
//  - each swizzled ds_read_b128 A-frag feeds 4 MFMAs (was 2)
//  - 32 independent 16B X-loads per thread (2x MLP)
//  - grid halves to 391: half the staging/barrier events
// Output layout, bias/2 fold, packed 8B stores: identical to r12 (bit-same).
// ---------------------------------------------------------------------------
__global__ __launch_bounds__(256)
void node_gemm_mfma(const float* __restrict__ X,
                    const short* __restrict__ Wpb,
                    const float* __restrict__ bias,
                    unsigned short* __restrict__ Ys, int M) {
    __shared__ short sW[NCH * NCH];          // 32 KB, swizzled 16B chunks
    const int t = threadIdx.x;

    // stage Wpb -> LDS: 2048 chunks of 16B; LDS chunk col swizzled: cc ^= row&7
    for (int it = 0; it < 8; ++it) {
        const int j   = it * 256 + t;
        const int row = j >> 4;
        const int cc  = j & 15;
        const int scc = cc ^ (row & 7);
        *reinterpret_cast<short8v*>(&sW[row * NCH + scc * 8]) =
            *reinterpret_cast<const short8v*>(Wpb + (size_t)j * 8);
    }
    __syncthreads();

    const int wave = t >> 6;
    const int lane = t & 63;
    const int r    = lane & 15;
    const int kb   = lane >> 4;

    const int nbase = blockIdx.x * 256 + wave * 64;

    // B-fragments (X rows) for 4 node groups
    short8v b[4][4];
    int node[4];
#pragma unroll
    for (int ng = 0; ng < 4; ++ng) {
        node[ng] = nbase + ng * 16 + r;
        const int nodec = node[ng] < M ? node[ng] : M - 1;   // stores guarded
        const float* xr = X + (size_t)nodec * NCH;
#pragma unroll
        for (int ks = 0; ks < 4; ++ks) {
            const float4 f0 = *reinterpret_cast<const float4*>(xr + ks * 32 + kb * 8);
            const float4 f1 = *reinterpret_cast<const float4*>(xr + ks * 32 + kb * 8 + 4);
            short8v v;
            v[0] = f2bf(f0.x); v[1] = f2bf(f0.y); v[2] = f2bf(f0.z); v[3] = f2bf(f0.w);
            v[4] = f2bf(f1.x); v[5] = f2bf(f1.y); v[6] = f2bf(f1.z); v[7] = f2bf(f1.w);
            b[ng][ks] = v;
        }
    }

#pragma unroll
    for (int tile = 0; tile < 8; ++tile) {
        f32x4 acc[4];
#pragma unroll
        for (int ng = 0; ng < 4; ++ng) acc[ng] = (f32x4){0.f, 0.f, 0.f, 0.f};
        const int row = tile * 16 + r;
#pragma unroll
        for (int ks = 0; ks < 4; ++ks) {
            const int cc = ks * 4 + kb;                       // unswizzled chunk col
            const short8v a = *reinterpret_cast<const short8v*>(
                &sW[row * NCH + (cc ^ (row & 7)) * 8]);
            acc[0] = __builtin_amdgcn_mfma_f32_16x16x32_bf16(a, b[0][ks], acc[0], 0, 0, 0);
            acc[1] = __builtin_amdgcn_mfma_f32_16x16x32_bf16(a, b[1][ks], acc[1], 0, 0, 0);
            acc[2] = __builtin_amdgcn_mfma_f32_16x16x32_bf16(a, b[2][ks], acc[2], 0, 0, 0);
            acc[3] = __builtin_amdgcn_mfma_f32_16x16x32_bf16(a, b[3][ks], acc[3], 0, 0, 0);
        }
        const float4 vb = *reinterpret_cast<const float4*>(bias + tile * 16 + kb * 4);
#pragma unroll
        for (int ng = 0; ng < 4; ++ng) {
            if (node[ng] < M) {
                ushort4v h;
                h[0] = f2h(acc[ng][0] + 0.5f * vb.x);
                h[1] = f2h(acc[ng][1] + 0.5f * vb.y);
                h[2] = f2h(acc[ng][2] + 0.5f * vb.z);
                h[3] = f2h(acc[ng][3] + 0.5f * vb.w);
                *reinterpret_cast<ushort4v*>(
                    Ys + (size_t)tile * M * 16 + (size_t)node[ng] * 16 + kb * 4) = h;
            }
        }
    }
}

// ---------------------------------------------------------------------------
// sliced edge kernel (byte-identical to r12 champion; at its equilibrium)
// ---------------------------------------------------------------------------
__global__ __launch_bounds__(256)
void edge_out_sliced(const unsigned short* __restrict__ Ys,
                     const int* __restrict__ ei,
                     float* __restrict__ out, int E, int M) {
    const unsigned bid = blockIdx.x;
    const int slice = bid & (NSLICE - 1);
    const int eblk  = bid >> 3;
    const int t  = threadIdx.x;
    const int cl = t & 3;
    const int e0 = eblk * 256 + (t >> 2);      // edges e0 + k*64, k=0..3

    const unsigned short* base = Ys + (size_t)slice * M * 16 + cl * 4;

    int s[4], g[4];
#pragma unroll
    for (int k = 0; k < 4; ++k) {
        const int e = e0 + k * 64;
        const int ec = e < E ? e : 0;
        s[k] = ei[ec];
        g[k] = ei[E + ec];
    }
    ushort4v hs[4], ht[4];
#pragma unroll
    for (int k = 0; k < 4; ++k) {
        hs[k] = gather8_l2(base + (size_t)s[k] * 16);
        ht[k] = gather8_l2(base + (size_t)g[k] * 16);
    }
#pragma unroll
    for (int k = 0; k < 4; ++k) {
        const int e = e0 + k * 64;
        if (e < E) {
            f32x4 r;
            r[0] = fmaxf(h2f(hs[k][0]) + h2f(ht[k][0]), 0.f);
            r[1] = fmaxf(h2f(hs[k][1]) + h2f(ht[k][1]), 0.f);
            r[2] = fmaxf(h2f(hs[k][2]) + h2f(ht[k][2]), 0.f);
            r[3] = fmaxf(h2f(hs[k][3]) + h2f(ht[k][3]), 0.f);
            f32x4* dst = reinterpret_cast<f32x4*>(
                out + (size_t)e * NCH + slice * 16 + cl * 4);
            __builtin_nontemporal_store(r, dst);
        }
    }
}

// ---------------------------------------------------------------------------
// fallback (only if ws too small): fully self-contained direct fp32 edge GEMM
// ---------------------------------------------------------------------------
__global__ __launch_bounds__(256)
void direct_edge_kernel(const float* __restrict__ X,
                        const int* __restrict__ ei,
                        const float* __restrict__ aw,
                        const float* __restrict__ W,
                        const float* __restrict__ bias,
                        float* __restrict__ out, int E) {
    __shared__ float sW[NCH][NCH + 1];
    __shared__ float sa[NCH];
    __shared__ float sE[8][NCH + 4];
    const int t = threadIdx.x;
    if (t < NCH) sa[t] = aw[t];
    __syncthreads();
    float m = -1e30f;
#pragma unroll
    for (int d = 0; d < NCH; ++d) m = fmaxf(m, sa[d]);
    float ssum = 0.f;
#pragma unroll
    for (int d = 0; d < NCH; ++d) ssum += expf(sa[d] - m);
    const float av = (t < NCH) ? expf(sa[t] - m) / ssum : 0.f;
    __syncthreads();
    if (t < NCH) sa[t] = av;
    __syncthreads();
    for (int i = t; i < NCH * 32; i += 256) {
        const int o = i >> 5, q = i & 31;
        float4 v = reinterpret_cast<const float4*>(W)[o * 32 + q];
        sW[o][q * 4 + 0] = v.x * sa[q * 4 + 0];
        sW[o][q * 4 + 1] = v.y * sa[q * 4 + 1];
        sW[o][q * 4 + 2] = v.z * sa[q * 4 + 2];
        sW[o][q * 4 + 3] = v.w * sa[q * 4 + 3];
    }
    __syncthreads();
    const int le = t >> 5, q = t & 31;
    for (int e0 = blockIdx.x * 8; e0 < E; e0 += gridDim.x * 8) {
        const int e = e0 + le;
        if (e < E) {
            const int s = ei[e];
            const int g = ei[E + e];
            const float4 vs = reinterpret_cast<const float4*>(X)[(size_t)s * 32 + q];
            const float4 vt = reinterpret_cast<const float4*>(X)[(size_t)g * 32 + q];
            sE[le][q * 4 + 0] = vs.x + vt.x;
            sE[le][q * 4 + 1] = vs.y + vt.y;
            sE[le][q * 4 + 2] = vs.z + vt.z;
            sE[le][q * 4 + 3] = vs.w + vt.w;
        }
        __syncthreads();
        if (e < E) {
            float a0 = 0.f, a1 = 0.f, a2 = 0.f, a3 = 0.f;
            const int o = q * 4;
#pragma unroll 4
            for (int d = 0; d < NCH; ++d) {
                const float x = sE[le][d];
                a0 += x * sW[o + 0][d];
                a1 += x * sW[o + 1][d];
                a2 += x * sW[o + 2][d];
                a3 += x * sW[o + 3][d];
            }
            float4 r;
            r.x = fmaxf(a0 + bias[o + 0], 0.f);
            r.y = fmaxf(a1 + bias[o + 1], 0.f);
            r.z = fmaxf(a2 + bias[o + 2], 0.f);
            r.w = fmaxf(a3 + bias[o + 3], 0.f);
            reinterpret_cast<float4*>(out)[(size_t)e * 32 + q] = r;
        }
        __syncthreads();
    }
}

// ---------------------------------------------------------------------------
extern "C" void kernel_launch(void* const* d_in, const int* in_sizes, int n_in,
                              void* d_out, int out_size, void* d_ws, size_t ws_size,
                              hipStream_t stream) {
    const float* X    = (const float*)d_in[0];   // [100000,128] f32
    const int*   ei   = (const int*)d_in[1];     // [2,625000] int32
    const float* aw   = (const float*)d_in[2];   // [128] f32
    const float* W    = (const float*)d_in[3];   // [128,128] f32
    const float* bias = (const float*)d_in[4];   // [128] f32
    float* out = (float*)d_out;

    const int M = in_sizes[0] / NCH;             // 100000 nodes
    const int E = in_sizes[1] / 2;               // 625000 edges

    const size_t y_off   = 65536;                                    // Wpb (32KB) + pad
    const size_t y_bytes = (size_t)M * NCH * sizeof(unsigned short); // 25.6 MB sliced

    if (ws_size >= y_off + y_bytes) {
        short* Wpb = (short*)d_ws;
        unsigned short* Ys = (unsigned short*)((char*)d_ws + y_off);
        prep_kernel<<<NCH, 128, 0, stream>>>(aw, W, Wpb);
        node_gemm_mfma<<<(M + 255) / 256, 256, 0, stream>>>(X, Wpb, bias, Ys, M);
        const int eblks = (E + 255) / 256;
        edge_out_sliced<<<eblks * NSLICE, 256, 0, stream>>>(Ys, ei, out, E, M);
    } else {
        int grid = (E + 7) / 8;
        if (grid > 32768) grid = 32768;
        direct_edge_kernel<<<grid, 256, 0, stream>>>(X, ei, aw, W, bias, out, E);
    }
}